// Round 1
// baseline (1902.904 us; speedup 1.0000x reference)
//
#include <hip/hip_runtime.h>

// ---------------------------------------------------------------------------
// GRU_13030930776564: bidirectional GRU, B=64, L=1024, DI=D=DO=256 (fp32 io).
// Plan:
//   P1: X  = bf16( inputs @ Wi + Wi_b )                        [65536 x 256]
//   P2: XX = bf16( X @ Wx + Wx_b )
//       XR = bf16( X @ Ux + Ux_b + Wr_b )   (fold recurrent bias)
//       XU = bf16( X @ Rx + Rx_b + Wu_b )
//   R : 8 WGs x 512 thr; WG = 16 sequences (batch x dir), weights-in-VGPR
//       MFMA (W = A-operand, h = B-operand from LDS), fp32 h state in regs,
//       1024 steps, one __syncthreads per step.
//   F : out = fp32( (Hf + Hb) @ Wo + Wo_b )
// ws layout (u16 elements, E = 64*1024*256): XX | XR | XU | Hf(=X) | Hb
//   -> needs 5*E*2 = 168 MB of workspace.
// ---------------------------------------------------------------------------

typedef float   f32x4 __attribute__((ext_vector_type(4)));
typedef short   s16x8 __attribute__((ext_vector_type(8)));
typedef unsigned int   u32;
typedef unsigned short u16;

#define LDP 264   // padded row stride in bf16 elements (528 B: 16B-aligned, <=2-way bank conflicts)

__device__ __forceinline__ u16 f2bf(float x) {
    u32 u = __float_as_uint(x);
    return (u16)((u + 0x7FFFu + ((u >> 16) & 1u)) >> 16);   // RNE, inputs never NaN
}
__device__ __forceinline__ float bflo(u32 u) { return __uint_as_float(u << 16); }
__device__ __forceinline__ float bfhi(u32 u) { return __uint_as_float(u & 0xFFFF0000u); }

__device__ __forceinline__ float sigm(float z) {
    float e = __builtin_amdgcn_exp2f(z * -1.44269504f);
    return __builtin_amdgcn_rcpf(1.0f + e);
}
__device__ __forceinline__ float tanhfast(float y) {
    float e = __builtin_amdgcn_exp2f(y * 2.88539008f);     // e^(2y)
    return 1.0f - 2.0f * __builtin_amdgcn_rcpf(1.0f + e);  // handles +/-inf saturation
}

// ---------------------------------------------------------------------------
// Generic K=256, N=256 GEMM: C[M x 256] = act-free (A @ W + b1 [+ b2]).
// A: fp32 or bf16 (optionally + A2 bf16 elementwise). C: fp32 or bf16.
// W (fp32, row-major [K][N]) is gathered once per WG into B-operand VGPR
// fragments (128 VGPRs). A strip of 32 rows staged in LDS per iteration.
// grid 512 (2 blocks/CU), block 256 (4 waves; wave w owns cols [w*64,w*64+64)).
// ---------------------------------------------------------------------------
__global__ __launch_bounds__(256, 2)
void gemm256(const void* __restrict__ Asrc, int a_f32, const u16* __restrict__ A2,
             const float* __restrict__ W, const float* __restrict__ b1,
             const float* __restrict__ b2, void* __restrict__ Cdst, int c_f32, int M)
{
    __shared__ u16 At[32 * LDP];
    const int tid  = threadIdx.x;
    const int lane = tid & 63, wv = tid >> 6;
    const int quad = lane >> 4, n16 = lane & 15;

    // preload B fragments: bw[nt][kt] holds W[k = kt*32+quad*8+j][col], col = wv*64+nt*16+n16
    s16x8 bw[4][8];
    #pragma unroll
    for (int nt = 0; nt < 4; ++nt) {
        const int col = wv * 64 + nt * 16 + n16;
        #pragma unroll
        for (int kt = 0; kt < 8; ++kt) {
            const int kb0 = kt * 32 + quad * 8;
            s16x8 f;
            #pragma unroll
            for (int j = 0; j < 8; ++j) f[j] = (short)f2bf(W[(kb0 + j) * 256 + col]);
            bw[nt][kt] = f;
        }
    }

    const int arow = tid >> 3, kb = (tid & 7) * 32;  // staging: 32 elements per thread
    float av[32];
    const int nstrip = M >> 5;

    for (int s = (int)blockIdx.x; s < nstrip; s += (int)gridDim.x) {
        // ---- load A strip (32 rows x 256) into regs ----
        const long base = (long)(s * 32 + arow) * 256 + kb;
        if (a_f32) {
            const float4* p = (const float4*)((const float*)Asrc + base);
            #pragma unroll
            for (int i = 0; i < 8; ++i) {
                float4 v = p[i];
                av[i*4+0] = v.x; av[i*4+1] = v.y; av[i*4+2] = v.z; av[i*4+3] = v.w;
            }
        } else {
            const uint4* p = (const uint4*)((const u16*)Asrc + base);
            #pragma unroll
            for (int i = 0; i < 4; ++i) {
                uint4 v = p[i];
                av[i*8+0] = bflo(v.x); av[i*8+1] = bfhi(v.x);
                av[i*8+2] = bflo(v.y); av[i*8+3] = bfhi(v.y);
                av[i*8+4] = bflo(v.z); av[i*8+5] = bfhi(v.z);
                av[i*8+6] = bflo(v.w); av[i*8+7] = bfhi(v.w);
            }
            if (A2) {
                const uint4* q = (const uint4*)(A2 + base);
                #pragma unroll
                for (int i = 0; i < 4; ++i) {
                    uint4 v = q[i];
                    av[i*8+0] += bflo(v.x); av[i*8+1] += bfhi(v.x);
                    av[i*8+2] += bflo(v.y); av[i*8+3] += bfhi(v.y);
                    av[i*8+4] += bflo(v.z); av[i*8+5] += bfhi(v.z);
                    av[i*8+6] += bflo(v.w); av[i*8+7] += bfhi(v.w);
                }
            }
        }
        __syncthreads();   // previous strip's MFMA reads of At complete
        {
            u16 tmp[32];
            #pragma unroll
            for (int i = 0; i < 32; ++i) tmp[i] = f2bf(av[i]);
            s16x8* dst = (s16x8*)&At[arow * LDP + kb];
            #pragma unroll
            for (int i = 0; i < 4; ++i) dst[i] = *(const s16x8*)&tmp[i * 8];
        }
        __syncthreads();   // At visible

        // ---- MFMA: 2 mtiles x 4 ntiles x 8 ktiles ----
        f32x4 acc[2][4];
        #pragma unroll
        for (int mt = 0; mt < 2; ++mt)
            #pragma unroll
            for (int nt = 0; nt < 4; ++nt) acc[mt][nt] = f32x4{0.f, 0.f, 0.f, 0.f};
        #pragma unroll
        for (int kt = 0; kt < 8; ++kt) {
            const int ko = kt * 32 + quad * 8;
            const s16x8 a0 = *(const s16x8*)&At[(n16) * LDP + ko];
            const s16x8 a1 = *(const s16x8*)&At[(16 + n16) * LDP + ko];
            #pragma unroll
            for (int nt = 0; nt < 4; ++nt) {
                acc[0][nt] = __builtin_amdgcn_mfma_f32_16x16x32_bf16(a0, bw[nt][kt], acc[0][nt], 0, 0, 0);
                acc[1][nt] = __builtin_amdgcn_mfma_f32_16x16x32_bf16(a1, bw[nt][kt], acc[1][nt], 0, 0, 0);
            }
        }

        // ---- epilogue: D row = quad*4+r (A-row), col = n16 (B-col) ----
        #pragma unroll
        for (int nt = 0; nt < 4; ++nt) {
            const int col = wv * 64 + nt * 16 + n16;
            const float bias = b1[col] + (b2 ? b2[col] : 0.0f);
            #pragma unroll
            for (int mt = 0; mt < 2; ++mt) {
                const int row0 = s * 32 + mt * 16 + quad * 4;
                #pragma unroll
                for (int r = 0; r < 4; ++r) {
                    const float v = acc[mt][nt][r] + bias;
                    const long idx = (long)(row0 + r) * 256 + col;
                    if (c_f32) ((float*)Cdst)[idx] = v;
                    else       ((u16*)Cdst)[idx]   = f2bf(v);
                }
            }
        }
    }
}

// ---------------------------------------------------------------------------
// Recurrence. 8 blocks x 512 threads. Block wg: dir = wg>>2, batches (wg&3)*16..+16.
// Wave w owns h-columns [w*32, w*32+32). Weights (Wr,Wu slices) preloaded as
// MFMA A-operand frags in 128 VGPRs. h state: fp32 in regs (lane owns
// seq = lane&15, cols quad*4+{0..3} and 16+quad*4+{0..3} of its wave slice);
// bf16 copy of full h[16][256] double-buffered in LDS as MFMA B-operand.
// x projections prefetched one step ahead (8 B loads). One barrier per step.
// ---------------------------------------------------------------------------
__global__ __launch_bounds__(512, 2)
void gru_rec(const u16* __restrict__ XX, const u16* __restrict__ XR, const u16* __restrict__ XU,
             const float* __restrict__ Wr, const float* __restrict__ Wu,
             u16* __restrict__ Hf, u16* __restrict__ Hb)
{
    __shared__ u16 hls[2][16 * LDP];
    const int tid  = threadIdx.x;
    const int lane = tid & 63, wave = tid >> 6;
    const int quad = lane >> 4, n16 = lane & 15;
    const int wg  = blockIdx.x;
    const int dir = wg >> 2;
    const int b   = (wg & 3) * 16 + n16;
    const int c0  = wave * 32;

    // ---- preload weight A-frags: aw[g][mt][kt], A[m=col][k] = W_g[k][col] ----
    s16x8 aw[2][2][8];
    #pragma unroll
    for (int g = 0; g < 2; ++g) {
        const float* Wg = g ? Wu : Wr;
        #pragma unroll
        for (int mt = 0; mt < 2; ++mt) {
            const int col = c0 + mt * 16 + n16;
            #pragma unroll
            for (int kt = 0; kt < 8; ++kt) {
                const int kb0 = kt * 32 + quad * 8;
                s16x8 f;
                #pragma unroll
                for (int j = 0; j < 8; ++j) f[j] = (short)f2bf(Wg[(kb0 + j) * 256 + col]);
                aw[g][mt][kt] = f;
            }
        }
    }

    for (int i = tid; i < 16 * LDP; i += 512) hls[0][i] = 0;   // h(0) = 0

    float h0v[4] = {0.f, 0.f, 0.f, 0.f};   // mt=0 cols
    float h1v[4] = {0.f, 0.f, 0.f, 0.f};   // mt=1 cols
    u16* Hg = dir ? Hb : Hf;
    const int  colb0 = c0 + quad * 4;
    const int  colb1 = c0 + 16 + quad * 4;
    const long rowb  = (long)b * 1024;

    uint2 xA[3][2], xB[3][2];
    {   // x for step 0
        const long off = (rowb + (dir ? 1023 : 0)) * 256;
        xA[0][0] = *(const uint2*)(XX + off + colb0);  xA[0][1] = *(const uint2*)(XX + off + colb1);
        xA[1][0] = *(const uint2*)(XR + off + colb0);  xA[1][1] = *(const uint2*)(XR + off + colb1);
        xA[2][0] = *(const uint2*)(XU + off + colb0);  xA[2][1] = *(const uint2*)(XU + off + colb1);
    }
    __syncthreads();

    auto stepbody = [&](int step, uint2 (&xc)[3][2], uint2 (&xn)[3][2],
                        const u16* hin, u16* hout) __attribute__((always_inline)) {
        const int t   = dir ? 1023 - step : step;
        int tn2 = step + 1; if (tn2 > 1023) tn2 = 1023;
        const int tn  = dir ? 1023 - tn2 : tn2;

        // prefetch next step's x (consumed next call; a full step of latency slack)
        const long offn = (rowb + tn) * 256;
        xn[0][0] = *(const uint2*)(XX + offn + colb0);  xn[0][1] = *(const uint2*)(XX + offn + colb1);
        xn[1][0] = *(const uint2*)(XR + offn + colb0);  xn[1][1] = *(const uint2*)(XR + offn + colb1);
        xn[2][0] = *(const uint2*)(XU + offn + colb0);  xn[2][1] = *(const uint2*)(XU + offn + colb1);

        // matvecs: D[m=col][n=seq] = sum_k W[k][col] * h[seq][k]
        f32x4 a00 = f32x4{0.f,0.f,0.f,0.f}, a01 = a00, a10 = a00, a11 = a00;
        #pragma unroll
        for (int kt = 0; kt < 8; ++kt) {
            const s16x8 hv = *(const s16x8*)(hin + n16 * LDP + kt * 32 + quad * 8);
            a00 = __builtin_amdgcn_mfma_f32_16x16x32_bf16(aw[0][0][kt], hv, a00, 0, 0, 0);
            a01 = __builtin_amdgcn_mfma_f32_16x16x32_bf16(aw[0][1][kt], hv, a01, 0, 0, 0);
            a10 = __builtin_amdgcn_mfma_f32_16x16x32_bf16(aw[1][0][kt], hv, a10, 0, 0, 0);
            a11 = __builtin_amdgcn_mfma_f32_16x16x32_bf16(aw[1][1][kt], hv, a11, 0, 0, 0);
        }

        const long off = (rowb + t) * 256;
        // ---- mt = 0 ----
        {
            const uint2 vxx = xc[0][0], vxr = xc[1][0], vxu = xc[2][0];
            const float xxv[4] = { bflo(vxx.x), bfhi(vxx.x), bflo(vxx.y), bfhi(vxx.y) };
            const float xrv[4] = { bflo(vxr.x), bfhi(vxr.x), bflo(vxr.y), bfhi(vxr.y) };
            const float xuv[4] = { bflo(vxu.x), bfhi(vxu.x), bflo(vxu.y), bfhi(vxu.y) };
            u16 hb16[4];
            #pragma unroll
            for (int r = 0; r < 4; ++r) {
                const float rr   = sigm(a00[r] + xrv[r]);
                const float uu   = sigm(a10[r] + xuv[r]);
                const float cand = tanhfast(rr * h0v[r] + xxv[r]);
                h0v[r] = cand + uu * (h0v[r] - cand);
                hb16[r] = f2bf(h0v[r]);
            }
            uint2 pk;
            pk.x = (u32)hb16[0] | ((u32)hb16[1] << 16);
            pk.y = (u32)hb16[2] | ((u32)hb16[3] << 16);
            *(uint2*)(hout + n16 * LDP + colb0) = pk;
            *(uint2*)(Hg + off + colb0) = pk;
        }
        // ---- mt = 1 ----
        {
            const uint2 vxx = xc[0][1], vxr = xc[1][1], vxu = xc[2][1];
            const float xxv[4] = { bflo(vxx.x), bfhi(vxx.x), bflo(vxx.y), bfhi(vxx.y) };
            const float xrv[4] = { bflo(vxr.x), bfhi(vxr.x), bflo(vxr.y), bfhi(vxr.y) };
            const float xuv[4] = { bflo(vxu.x), bfhi(vxu.x), bflo(vxu.y), bfhi(vxu.y) };
            u16 hb16[4];
            #pragma unroll
            for (int r = 0; r < 4; ++r) {
                const float rr   = sigm(a01[r] + xrv[r]);
                const float uu   = sigm(a11[r] + xuv[r]);
                const float cand = tanhfast(rr * h1v[r] + xxv[r]);
                h1v[r] = cand + uu * (h1v[r] - cand);
                hb16[r] = f2bf(h1v[r]);
            }
            uint2 pk;
            pk.x = (u32)hb16[0] | ((u32)hb16[1] << 16);
            pk.y = (u32)hb16[2] | ((u32)hb16[3] << 16);
            *(uint2*)(hout + n16 * LDP + colb1) = pk;
            *(uint2*)(Hg + off + colb1) = pk;
        }
        __syncthreads();   // h(t+1) in hout visible to all waves
    };

    u16* const hb0 = &hls[0][0];
    u16* const hb1 = &hls[1][0];
    for (int sp = 0; sp < 512; ++sp) {
        stepbody(sp * 2,     xA, xB, hb0, hb1);
        stepbody(sp * 2 + 1, xB, xA, hb1, hb0);
    }
}

// ---------------------------------------------------------------------------
extern "C" void kernel_launch(void* const* d_in, const int* in_sizes, int n_in,
                              void* d_out, int out_size, void* d_ws, size_t ws_size,
                              hipStream_t stream)
{
    const float* inputs = (const float*)d_in[0];
    const float* Wi_w = (const float*)d_in[1];
    const float* Wi_b = (const float*)d_in[2];
    const float* Wx_w = (const float*)d_in[3];
    const float* Wx_b = (const float*)d_in[4];
    const float* Ux_w = (const float*)d_in[5];
    const float* Ux_b = (const float*)d_in[6];
    const float* Rx_w = (const float*)d_in[7];
    const float* Rx_b = (const float*)d_in[8];
    const float* Wr_w = (const float*)d_in[9];
    const float* Wr_b = (const float*)d_in[10];
    const float* Wu_w = (const float*)d_in[11];
    const float* Wu_b = (const float*)d_in[12];
    const float* Wo_w = (const float*)d_in[13];
    const float* Wo_b = (const float*)d_in[14];

    const long E = 64L * 1024 * 256;
    u16* XX = (u16*)d_ws;
    u16* XR = XX + E;
    u16* XU = XR + E;
    u16* Hf = XU + E;      // also used as X (bf16) between P1 and P2 — dead before R writes it
    u16* Hb = Hf + E;
    u16* Xb = Hf;

    const int M = 64 * 1024;
    const dim3 gg(512), gb(256);

    // P1: X = inputs @ Wi + Wi_b
    hipLaunchKernelGGL(gemm256, gg, gb, 0, stream,
                       (const void*)inputs, 1, (const u16*)nullptr, Wi_w, Wi_b, (const float*)nullptr,
                       (void*)Xb, 0, M);
    // P2: gate input projections (recurrent biases folded in)
    hipLaunchKernelGGL(gemm256, gg, gb, 0, stream,
                       (const void*)Xb, 0, (const u16*)nullptr, Wx_w, Wx_b, (const float*)nullptr,
                       (void*)XX, 0, M);
    hipLaunchKernelGGL(gemm256, gg, gb, 0, stream,
                       (const void*)Xb, 0, (const u16*)nullptr, Ux_w, Ux_b, Wr_b,
                       (void*)XR, 0, M);
    hipLaunchKernelGGL(gemm256, gg, gb, 0, stream,
                       (const void*)Xb, 0, (const u16*)nullptr, Rx_w, Rx_b, Wu_b,
                       (void*)XU, 0, M);
    // R: the sequential scan (both directions concurrently)
    hipLaunchKernelGGL(gru_rec, dim3(8), dim3(512), 0, stream,
                       (const u16*)XX, (const u16*)XR, (const u16*)XU, Wr_w, Wu_w, Hf, Hb);
    // F: out = (Hf + Hb) @ Wo + Wo_b
    hipLaunchKernelGGL(gemm256, gg, gb, 0, stream,
                       (const void*)Hf, 0, (const u16*)Hb, Wo_w, Wo_b, (const float*)nullptr,
                       d_out, 1, M);
}

// Round 2
// 1165.229 us; speedup vs baseline: 1.6331x; 1.6331x over previous
//
#include <hip/hip_runtime.h>

// ---------------------------------------------------------------------------
// GRU_13030930776564: bidirectional GRU, B=64, L=1024, DI=D=DO=256 (fp32 io).
//   P1: X  = bf16( inputs @ Wi + Wi_b )                        [65536 x 256]
//   P2: XX = bf16( X @ Wx + Wx_b )
//       XR = bf16( X @ Ux + Ux_b + Wr_b )   (fold recurrent bias)
//       XU = bf16( X @ Rx + Rx_b + Wu_b )
//   R : 64 WGs x 512 thr; WG = 2 sequences (batch x dir). Weights-in-VGPR
//       MFMA (W = A-operand m=col, h = B-operand n=seq from LDS).
//       D-lanes n16>=2 are M-dim waste (MFMA is not the binding pipe);
//       pre-activations are redistributed to all 64 lanes via a wave-private
//       LDS transpose (no extra barrier) -> 1 elementwise element per lane.
//       fp32 h state in regs, 1024 steps, ONE __syncthreads per step
//       (h LDS double-buffered).
//   F : out = fp32( (Hf + Hb) @ Wo + Wo_b )
// ws layout (u16 elements, E = 64*1024*256): XX | XR | XU | Hf(=X) | Hb
// ---------------------------------------------------------------------------

typedef float   f32x4 __attribute__((ext_vector_type(4)));
typedef short   s16x8 __attribute__((ext_vector_type(8)));
typedef unsigned int   u32;
typedef unsigned short u16;

#define LDP 264   // padded row stride in bf16 elements

__device__ __forceinline__ u16 f2bf(float x) {
    u32 u = __float_as_uint(x);
    return (u16)((u + 0x7FFFu + ((u >> 16) & 1u)) >> 16);   // RNE, inputs never NaN
}
__device__ __forceinline__ float bflo(u32 u) { return __uint_as_float(u << 16); }
__device__ __forceinline__ float bfhi(u32 u) { return __uint_as_float(u & 0xFFFF0000u); }
__device__ __forceinline__ float bf2f(u16 v) { return __uint_as_float((u32)v << 16); }

__device__ __forceinline__ float sigm(float z) {
    float e = __builtin_amdgcn_exp2f(z * -1.44269504f);
    return __builtin_amdgcn_rcpf(1.0f + e);
}
__device__ __forceinline__ float tanhfast(float y) {
    float e = __builtin_amdgcn_exp2f(y * 2.88539008f);     // e^(2y)
    return 1.0f - 2.0f * __builtin_amdgcn_rcpf(1.0f + e);  // handles +/-inf saturation
}

// ---------------------------------------------------------------------------
// Generic K=256, N=256 GEMM: C[M x 256] = A @ W + b1 [+ b2].  (unchanged R1)
// ---------------------------------------------------------------------------
__global__ __launch_bounds__(256, 2)
void gemm256(const void* __restrict__ Asrc, int a_f32, const u16* __restrict__ A2,
             const float* __restrict__ W, const float* __restrict__ b1,
             const float* __restrict__ b2, void* __restrict__ Cdst, int c_f32, int M)
{
    __shared__ u16 At[32 * LDP];
    const int tid  = threadIdx.x;
    const int lane = tid & 63, wv = tid >> 6;
    const int quad = lane >> 4, n16 = lane & 15;

    // preload B fragments: bw[nt][kt] holds W[k = kt*32+quad*8+j][col], col = wv*64+nt*16+n16
    s16x8 bw[4][8];
    #pragma unroll
    for (int nt = 0; nt < 4; ++nt) {
        const int col = wv * 64 + nt * 16 + n16;
        #pragma unroll
        for (int kt = 0; kt < 8; ++kt) {
            const int kb0 = kt * 32 + quad * 8;
            s16x8 f;
            #pragma unroll
            for (int j = 0; j < 8; ++j) f[j] = (short)f2bf(W[(kb0 + j) * 256 + col]);
            bw[nt][kt] = f;
        }
    }

    const int arow = tid >> 3, kb = (tid & 7) * 32;  // staging: 32 elements per thread
    float av[32];
    const int nstrip = M >> 5;

    for (int s = (int)blockIdx.x; s < nstrip; s += (int)gridDim.x) {
        // ---- load A strip (32 rows x 256) into regs ----
        const long base = (long)(s * 32 + arow) * 256 + kb;
        if (a_f32) {
            const float4* p = (const float4*)((const float*)Asrc + base);
            #pragma unroll
            for (int i = 0; i < 8; ++i) {
                float4 v = p[i];
                av[i*4+0] = v.x; av[i*4+1] = v.y; av[i*4+2] = v.z; av[i*4+3] = v.w;
            }
        } else {
            const uint4* p = (const uint4*)((const u16*)Asrc + base);
            #pragma unroll
            for (int i = 0; i < 4; ++i) {
                uint4 v = p[i];
                av[i*8+0] = bflo(v.x); av[i*8+1] = bfhi(v.x);
                av[i*8+2] = bflo(v.y); av[i*8+3] = bfhi(v.y);
                av[i*8+4] = bflo(v.z); av[i*8+5] = bfhi(v.z);
                av[i*8+6] = bflo(v.w); av[i*8+7] = bfhi(v.w);
            }
            if (A2) {
                const uint4* q = (const uint4*)(A2 + base);
                #pragma unroll
                for (int i = 0; i < 4; ++i) {
                    uint4 v = q[i];
                    av[i*8+0] += bflo(v.x); av[i*8+1] += bfhi(v.x);
                    av[i*8+2] += bflo(v.y); av[i*8+3] += bfhi(v.y);
                    av[i*8+4] += bflo(v.z); av[i*8+5] += bfhi(v.z);
                    av[i*8+6] += bflo(v.w); av[i*8+7] += bfhi(v.w);
                }
            }
        }
        __syncthreads();   // previous strip's MFMA reads of At complete
        {
            u16 tmp[32];
            #pragma unroll
            for (int i = 0; i < 32; ++i) tmp[i] = f2bf(av[i]);
            s16x8* dst = (s16x8*)&At[arow * LDP + kb];
            #pragma unroll
            for (int i = 0; i < 4; ++i) dst[i] = *(const s16x8*)&tmp[i * 8];
        }
        __syncthreads();   // At visible

        // ---- MFMA: 2 mtiles x 4 ntiles x 8 ktiles ----
        f32x4 acc[2][4];
        #pragma unroll
        for (int mt = 0; mt < 2; ++mt)
            #pragma unroll
            for (int nt = 0; nt < 4; ++nt) acc[mt][nt] = f32x4{0.f, 0.f, 0.f, 0.f};
        #pragma unroll
        for (int kt = 0; kt < 8; ++kt) {
            const int ko = kt * 32 + quad * 8;
            const s16x8 a0 = *(const s16x8*)&At[(n16) * LDP + ko];
            const s16x8 a1 = *(const s16x8*)&At[(16 + n16) * LDP + ko];
            #pragma unroll
            for (int nt = 0; nt < 4; ++nt) {
                acc[0][nt] = __builtin_amdgcn_mfma_f32_16x16x32_bf16(a0, bw[nt][kt], acc[0][nt], 0, 0, 0);
                acc[1][nt] = __builtin_amdgcn_mfma_f32_16x16x32_bf16(a1, bw[nt][kt], acc[1][nt], 0, 0, 0);
            }
        }

        // ---- epilogue: D row = quad*4+r (A-row), col = n16 (B-col) ----
        #pragma unroll
        for (int nt = 0; nt < 4; ++nt) {
            const int col = wv * 64 + nt * 16 + n16;
            const float bias = b1[col] + (b2 ? b2[col] : 0.0f);
            #pragma unroll
            for (int mt = 0; mt < 2; ++mt) {
                const int row0 = s * 32 + mt * 16 + quad * 4;
                #pragma unroll
                for (int r = 0; r < 4; ++r) {
                    const float v = acc[mt][nt][r] + bias;
                    const long idx = (long)(row0 + r) * 256 + col;
                    if (c_f32) ((float*)Cdst)[idx] = v;
                    else       ((u16*)Cdst)[idx]   = f2bf(v);
                }
            }
        }
    }
}

// ---------------------------------------------------------------------------
// Recurrence. 64 blocks x 512 threads. Block wg: dir = wg>>5, batches b0=(wg&31)*2.
// Wave w owns h-columns [w*32, w*32+32), both gates: aw[2 gates][2 mtiles][8 kt]
// = 128 VGPRs. MFMA B-operand: h rows (n16&1) from LDS (double-buffered,
// broadcast reads). Pre-acts (only lanes n16<2 valid) transposed through a
// wave-private LDS scratch -> every lane does elementwise for exactly one
// (seq, col). fp32 h state per lane. One __syncthreads per step.
// ---------------------------------------------------------------------------
__global__ __launch_bounds__(512, 2)
void gru_rec(const u16* __restrict__ XX, const u16* __restrict__ XR, const u16* __restrict__ XU,
             const float* __restrict__ Wr, const float* __restrict__ Wu,
             u16* __restrict__ Hf, u16* __restrict__ Hb)
{
    __shared__ u16   hbuf[2][2 * LDP];   // [buf][seq*LDP + col]
    __shared__ float scr[8 * 128];       // [wave][seq*64 + cl*2 + {r,u}]

    const int tid  = threadIdx.x;
    const int lane = tid & 63, wave = tid >> 6;
    const int quad = lane >> 4, n16 = lane & 15;
    const int wg  = blockIdx.x;
    const int dir = wg >> 5;             // 0 fwd, 1 bwd
    const int b0  = (wg & 31) * 2;       // two batches: b0, b0+1
    const int c0  = wave * 32;

    // ---- preload weight A-frags: aw[g][mt][kt], A[m=col][k] = W_g[k][col] ----
    s16x8 aw[2][2][8];
    #pragma unroll
    for (int g = 0; g < 2; ++g) {
        const float* Wg = g ? Wu : Wr;
        #pragma unroll
        for (int mt = 0; mt < 2; ++mt) {
            const int col = c0 + mt * 16 + n16;
            #pragma unroll
            for (int kt = 0; kt < 8; ++kt) {
                const int kb0 = kt * 32 + quad * 8;
                s16x8 f;
                #pragma unroll
                for (int j = 0; j < 8; ++j) f[j] = (short)f2bf(Wg[(kb0 + j) * 256 + col]);
                aw[g][mt][kt] = f;
            }
        }
    }

    // elementwise identity: one (seq, col) per lane
    const int  eseq = lane >> 5;                 // 0..1
    const int  ecl  = lane & 31;                 // 0..31
    const int  gcol = c0 + ecl;                  // global h column
    const long xrow = (long)(b0 + eseq) * 1024;  // row base within [B*L]
    float hprev = 0.0f;

    for (int i = tid; i < 2 * LDP; i += 512) hbuf[0][i] = 0;   // h(0) = 0

    u16* const Hg = dir ? Hb : Hf;

    // x for step 0
    u16 cxx, cxr, cxu;
    {
        const long off = (xrow + (dir ? 1023 : 0)) * 256 + gcol;
        cxx = XX[off]; cxr = XR[off]; cxu = XU[off];
    }
    __syncthreads();

    auto stepbody = [&](int step, int pb) __attribute__((always_inline)) {
        const int t = dir ? 1023 - step : step;
        int sn = step + 1; if (sn > 1023) sn = 1023;
        const int tn = dir ? 1023 - sn : sn;

        // prefetch next step's x (full step of latency slack)
        const long offn = (xrow + tn) * 256 + gcol;
        const u16 nxx = XX[offn], nxr = XR[offn], nxu = XU[offn];

        // ---- matvecs: D[m=col][n=seq] = sum_k W[k][col] * h[seq][k] ----
        const u16* hin = &hbuf[pb][0];
        f32x4 a00 = f32x4{0.f,0.f,0.f,0.f}, a01 = a00, a10 = a00, a11 = a00;
        #pragma unroll
        for (int kt = 0; kt < 8; ++kt) {
            const s16x8 hv = *(const s16x8*)(hin + (n16 & 1) * LDP + kt * 32 + quad * 8);
            a00 = __builtin_amdgcn_mfma_f32_16x16x32_bf16(aw[0][0][kt], hv, a00, 0, 0, 0);
            a01 = __builtin_amdgcn_mfma_f32_16x16x32_bf16(aw[0][1][kt], hv, a01, 0, 0, 0);
            a10 = __builtin_amdgcn_mfma_f32_16x16x32_bf16(aw[1][0][kt], hv, a10, 0, 0, 0);
            a11 = __builtin_amdgcn_mfma_f32_16x16x32_bf16(aw[1][1][kt], hv, a11, 0, 0, 0);
        }

        // ---- wave-private transpose: (r_pre,u_pre) pairs -> scr[seq][col] ----
        // src lane (n16=seq<2, quad): acc[g][mt][r] is (gate g, col mt*16+quad*4+r)
        if (n16 < 2) {
            float* p = &scr[wave * 128 + n16 * 64 + quad * 8];
            *(f32x4*)(p)      = f32x4{ a00[0], a10[0], a00[1], a10[1] };   // mt0 r=0,1
            *(f32x4*)(p + 4)  = f32x4{ a00[2], a10[2], a00[3], a10[3] };   // mt0 r=2,3
            *(f32x4*)(p + 32) = f32x4{ a01[0], a11[0], a01[1], a11[1] };   // mt1 r=0,1
            *(f32x4*)(p + 36) = f32x4{ a01[2], a11[2], a01[3], a11[3] };   // mt1 r=2,3
        }
        __builtin_amdgcn_wave_barrier();   // keep write->read order (same wave, lgkmcnt)
        const float2 pre = *(const float2*)&scr[wave * 128 + eseq * 64 + ecl * 2];

        // ---- elementwise: exactly one (seq, col) per lane ----
        const float rr   = sigm(pre.x + bf2f(cxr));
        const float uu   = sigm(pre.y + bf2f(cxu));
        const float cand = tanhfast(rr * hprev + bf2f(cxx));
        hprev = cand + uu * (hprev - cand);
        const u16 h16 = f2bf(hprev);

        hbuf[pb ^ 1][eseq * LDP + gcol] = h16;        // next step's B-operand
        Hg[(xrow + t) * 256 + gcol]     = h16;        // persist for F-GEMM

        cxx = nxx; cxr = nxr; cxu = nxu;
        __syncthreads();                              // hbuf[pb^1] visible
    };

    for (int sp = 0; sp < 512; ++sp) {
        stepbody(sp * 2,     0);
        stepbody(sp * 2 + 1, 1);
    }
}

// ---------------------------------------------------------------------------
extern "C" void kernel_launch(void* const* d_in, const int* in_sizes, int n_in,
                              void* d_out, int out_size, void* d_ws, size_t ws_size,
                              hipStream_t stream)
{
    const float* inputs = (const float*)d_in[0];
    const float* Wi_w = (const float*)d_in[1];
    const float* Wi_b = (const float*)d_in[2];
    const float* Wx_w = (const float*)d_in[3];
    const float* Wx_b = (const float*)d_in[4];
    const float* Ux_w = (const float*)d_in[5];
    const float* Ux_b = (const float*)d_in[6];
    const float* Rx_w = (const float*)d_in[7];
    const float* Rx_b = (const float*)d_in[8];
    const float* Wr_w = (const float*)d_in[9];
    const float* Wr_b = (const float*)d_in[10];
    const float* Wu_w = (const float*)d_in[11];
    const float* Wu_b = (const float*)d_in[12];
    const float* Wo_w = (const float*)d_in[13];
    const float* Wo_b = (const float*)d_in[14];

    const long E = 64L * 1024 * 256;
    u16* XX = (u16*)d_ws;
    u16* XR = XX + E;
    u16* XU = XR + E;
    u16* Hf = XU + E;      // also used as X (bf16) between P1 and P2 — dead before R writes it
    u16* Hb = Hf + E;
    u16* Xb = Hf;

    const int M = 64 * 1024;
    const dim3 gg(512), gb(256);

    // P1: X = inputs @ Wi + Wi_b
    hipLaunchKernelGGL(gemm256, gg, gb, 0, stream,
                       (const void*)inputs, 1, (const u16*)nullptr, Wi_w, Wi_b, (const float*)nullptr,
                       (void*)Xb, 0, M);
    // P2: gate input projections (recurrent biases folded in)
    hipLaunchKernelGGL(gemm256, gg, gb, 0, stream,
                       (const void*)Xb, 0, (const u16*)nullptr, Wx_w, Wx_b, (const float*)nullptr,
                       (void*)XX, 0, M);
    hipLaunchKernelGGL(gemm256, gg, gb, 0, stream,
                       (const void*)Xb, 0, (const u16*)nullptr, Ux_w, Ux_b, Wr_b,
                       (void*)XR, 0, M);
    hipLaunchKernelGGL(gemm256, gg, gb, 0, stream,
                       (const void*)Xb, 0, (const u16*)nullptr, Rx_w, Rx_b, Wu_b,
                       (void*)XU, 0, M);
    // R: the sequential scan (both directions concurrently, 64 WGs)
    hipLaunchKernelGGL(gru_rec, dim3(64), dim3(512), 0, stream,
                       (const u16*)XX, (const u16*)XR, (const u16*)XU, Wr_w, Wu_w, Hf, Hb);
    // F: out = (Hf + Hb) @ Wo + Wo_b
    hipLaunchKernelGGL(gemm256, gg, gb, 0, stream,
                       (const void*)Hf, 0, (const u16*)Hb, Wo_w, Wo_b, (const float*)nullptr,
                       d_out, 1, M);
}